// Round 2
// baseline (1283.119 us; speedup 1.0000x reference)
//
#include <hip/hip_runtime.h>
#include <stdint.h>

#define HEADS 12
#define HD 32
#define NTOK 49
#define DIM 384
#define SCALE 0.17677669529663687f

typedef __attribute__((ext_vector_type(8))) short s8v;   // 8 bf16 (4 VGPRs) MFMA A/B frag
typedef __attribute__((ext_vector_type(4))) float f4v;   // MFMA C/D frag

__device__ __forceinline__ unsigned short f2bf(float f) {
    union { float f; unsigned int i; } c; c.f = f;
    unsigned int x = c.i;
    return (unsigned short)((x + 0x7FFFu + ((x >> 16) & 1u)) >> 16);
}

// load 8 consecutive fp32 (32B, 16B-aligned) -> bf16x8 fragment
__device__ __forceinline__ s8v load_pack8(const float* p) {
    float4 a = *(const float4*)p;
    float4 b = *(const float4*)(p + 4);
    s8v r;
    r[0] = (short)f2bf(a.x); r[1] = (short)f2bf(a.y);
    r[2] = (short)f2bf(a.z); r[3] = (short)f2bf(a.w);
    r[4] = (short)f2bf(b.x); r[5] = (short)f2bf(b.y);
    r[6] = (short)f2bf(b.z); r[7] = (short)f2bf(b.w);
    return r;
}

// LDS layout (ushort units). Total 12032 ushorts = 24064 B.
#define QK_OFF 0        // q,k: [2][64 tokens][40 (32+8 pad)]  = 5120
#define VT_OFF 5120     // v^T: [32 d][72 (64+8 pad) tokens]   = 2304
#define U_OFF  7424     // union: wlds [96][40]=3840 | plds [64][72]=4608 | ho [64][40]=2560
#define LDS_TOT 12032

__global__ __launch_bounds__(256, 2) void winattn_fused(
    const float* __restrict__ xg,              // [B,49,384] fp32
    const unsigned char* __restrict__ maskg,   // [64,49,49] bool (all false)
    const float* __restrict__ qkvw,            // [1152,384] fp32
    const float* __restrict__ qkvb,            // [1152] fp32
    const float* __restrict__ projw,           // [384,384] fp32
    const float* __restrict__ projb,           // [384] fp32
    const float* __restrict__ rpb,             // [169,12] fp32
    const int*   __restrict__ relidx,          // [49,49] int32
    float*       __restrict__ outg)            // [B,49,384] fp32
{
    __shared__ __align__(16) unsigned short lds[LDS_TOT];
    const int tid = threadIdx.x;
    const int w   = tid >> 6;     // wave 0..3
    const int l   = tid & 63;
    const int l15 = l & 15;
    const int lq  = l >> 4;       // 0..3
    const int b   = blockIdx.x;

    const float*         xw    = xg + (size_t)b * (NTOK * DIM);
    const unsigned char* maskw = maskg + (size_t)(b & 63) * (NTOK * NTOK);

    // ---- x A-fragments: row fixed per lane for whole kernel (pad rows 49..63 clamp to row 48)
    const int arow = min(w * 16 + l15, NTOK - 1);
    s8v xa[12];
#pragma unroll
    for (int ks = 0; ks < 12; ++ks)
        xa[ks] = load_pack8(xw + arow * DIM + ks * 32 + lq * 8);

    // ---- bias byte-offsets into rpb rows; -1 sentinel => score := -1e30 (mask / padded col)
    int boff[4][4];
#pragma unroll
    for (int nt = 0; nt < 4; ++nt)
#pragma unroll
        for (int reg = 0; reg < 4; ++reg) {
            int i = w * 16 + lq * 4 + reg;     // score row (query token)
            int j = nt * 16 + l15;             // score col (key token)
            if (i < NTOK && j < NTOK)
                boff[nt][reg] = maskw[i * NTOK + j] ? -1 : relidx[i * NTOK + j] * (HEADS * 4);
            else
                boff[nt][reg] = (j >= NTOK) ? -1 : 0;  // i>=49: don't-care row, keep finite
        }

    const f4v fz = {0.f, 0.f, 0.f, 0.f};
    f4v oc[4][6];                               // persistent out accumulator
#pragma unroll
    for (int mt = 0; mt < 4; ++mt)
#pragma unroll
        for (int j = 0; j < 6; ++j) oc[mt][j] = fz;

    for (int h = 0; h < HEADS; ++h) {
        __syncthreads();                        // U region reuse guard

        // ======== Phase A: qkv_head = x @ W3h^T  (M=64 pad, N=96, K=384) ========
        f4v acc[6];
#pragma unroll
        for (int nt = 0; nt < 6; ++nt) acc[nt] = fz;
#pragma unroll
        for (int ks = 0; ks < 12; ++ks) {
            for (int idx = tid; idx < 384; idx += 256) {
                int c = idx >> 2, part = idx & 3;
                int rowsel = (c >> 5) * DIM + h * HD + (c & 31);
                *(s8v*)(&lds[U_OFF + c * 40 + part * 8]) =
                    load_pack8(qkvw + rowsel * DIM + ks * 32 + part * 8);
            }
            __syncthreads();
            s8v a = xa[ks];
#pragma unroll
            for (int nt = 0; nt < 6; ++nt) {
                s8v bf = *(const s8v*)(&lds[U_OFF + (nt * 16 + l15) * 40 + lq * 8]);
                acc[nt] = __builtin_amdgcn_mfma_f32_16x16x32_bf16(a, bf, acc[nt], 0, 0, 0);
            }
            __syncthreads();
        }
        // bias + scale; q,k -> QK; v -> VT (transposed [d][token])
#pragma unroll
        for (int nt = 0; nt < 6; ++nt) {
            int c96 = nt * 16 + l15;
            int sect = c96 >> 5;                // 0=q 1=k 2=v
            int cc = c96 & 31;
            float bias = qkvb[sect * DIM + h * HD + cc];
#pragma unroll
            for (int reg = 0; reg < 4; ++reg) {
                int row = w * 16 + lq * 4 + reg;
                float v = acc[nt][reg] + bias;
                if (sect == 0) v *= SCALE;
                unsigned short bv = f2bf(v);
                if (sect < 2) lds[QK_OFF + sect * 2560 + row * 40 + cc] = bv;
                else          lds[VT_OFF + cc * 72 + row] = bv;
            }
        }
        __syncthreads();

        // ======== Phase B: scores, bias, mask, softmax in regs ========
        s8v qa = *(const s8v*)(&lds[QK_OFF + (w * 16 + l15) * 40 + lq * 8]);
        f4v sc[4];
#pragma unroll
        for (int nt = 0; nt < 4; ++nt) {
            s8v kb = *(const s8v*)(&lds[QK_OFF + 2560 + (nt * 16 + l15) * 40 + lq * 8]);
            sc[nt] = __builtin_amdgcn_mfma_f32_16x16x32_bf16(qa, kb, fz, 0, 0, 0);
        }
        const char* rpbb = (const char*)rpb + h * 4;
#pragma unroll
        for (int nt = 0; nt < 4; ++nt)
#pragma unroll
            for (int reg = 0; reg < 4; ++reg) {
                int bo = boff[nt][reg];
                float v = sc[nt][reg] + *(const float*)(rpbb + (bo < 0 ? 0 : bo));
                sc[nt][reg] = (bo < 0) ? -1e30f : v;
            }
#pragma unroll
        for (int reg = 0; reg < 4; ++reg) {
            float m = fmaxf(fmaxf(sc[0][reg], sc[1][reg]), fmaxf(sc[2][reg], sc[3][reg]));
            m = fmaxf(m, __shfl_xor(m, 1));
            m = fmaxf(m, __shfl_xor(m, 2));
            m = fmaxf(m, __shfl_xor(m, 4));
            m = fmaxf(m, __shfl_xor(m, 8));
            float e0 = __expf(sc[0][reg] - m);
            float e1 = __expf(sc[1][reg] - m);
            float e2 = __expf(sc[2][reg] - m);
            float e3 = __expf(sc[3][reg] - m);
            float t = (e0 + e1) + (e2 + e3);
            t += __shfl_xor(t, 1);
            t += __shfl_xor(t, 2);
            t += __shfl_xor(t, 4);
            t += __shfl_xor(t, 8);
            float inv = 1.0f / t;
            sc[0][reg] = e0 * inv; sc[1][reg] = e1 * inv;
            sc[2][reg] = e2 * inv; sc[3][reg] = e3 * inv;
        }
        // P -> plds (own rows only; same-wave round trip)
#pragma unroll
        for (int nt = 0; nt < 4; ++nt)
#pragma unroll
            for (int reg = 0; reg < 4; ++reg) {
                int row = w * 16 + lq * 4 + reg;
                lds[U_OFF + row * 72 + nt * 16 + l15] = f2bf(sc[nt][reg]);
            }

        // ======== Phase C: head_out = P @ V  (M=16/wave, N=32, K=64) ========
        f4v ho[2] = {fz, fz};
#pragma unroll
        for (int ks = 0; ks < 2; ++ks) {
            s8v pa = *(const s8v*)(&lds[U_OFF + (w * 16 + l15) * 72 + ks * 32 + lq * 8]);
#pragma unroll
            for (int nt = 0; nt < 2; ++nt) {
                s8v vb = *(const s8v*)(&lds[VT_OFF + (nt * 16 + l15) * 72 + ks * 32 + lq * 8]);
                ho[nt] = __builtin_amdgcn_mfma_f32_16x16x32_bf16(pa, vb, ho[nt], 0, 0, 0);
            }
        }
        __syncthreads();   // all plds reads done before ho overwrites U
#pragma unroll
        for (int nt = 0; nt < 2; ++nt)
#pragma unroll
            for (int reg = 0; reg < 4; ++reg) {
                int row = w * 16 + lq * 4 + reg;
                lds[U_OFF + row * 40 + nt * 16 + l15] = f2bf(ho[nt][reg]);
            }
        __syncthreads();   // ho visible cross-wave

        // ======== Phase D: out += head_out @ proj_w[:, h*32:+32]^T ========
        s8v ha[4];
#pragma unroll
        for (int mt = 0; mt < 4; ++mt)
            ha[mt] = *(const s8v*)(&lds[U_OFF + (mt * 16 + l15) * 40 + lq * 8]);
#pragma unroll
        for (int j = 0; j < 6; ++j) {
            int col = (w * 6 + j) * 16 + l15;
            s8v pb = load_pack8(projw + col * DIM + h * HD + lq * 8);
#pragma unroll
            for (int mt = 0; mt < 4; ++mt)
                oc[mt][j] = __builtin_amdgcn_mfma_f32_16x16x32_bf16(ha[mt], pb, oc[mt][j], 0, 0, 0);
        }
    }

    // ======== epilogue: + proj_b, store fp32 (rows < 49) ========
#pragma unroll
    for (int j = 0; j < 6; ++j) {
        int col = (w * 6 + j) * 16 + l15;
        float pbv = projb[col];
#pragma unroll
        for (int mt = 0; mt < 4; ++mt)
#pragma unroll
            for (int reg = 0; reg < 4; ++reg) {
                int row = mt * 16 + lq * 4 + reg;
                if (row < NTOK)
                    outg[(size_t)b * (NTOK * DIM) + row * DIM + col] =
                        oc[mt][j][reg] + pbv;
            }
    }
}

extern "C" void kernel_launch(void* const* d_in, const int* in_sizes, int n_in,
                              void* d_out, int out_size, void* d_ws, size_t ws_size,
                              hipStream_t stream) {
    (void)n_in; (void)d_ws; (void)ws_size; (void)out_size;
    const int B = in_sizes[0] / (NTOK * DIM);   // 2048
    hipLaunchKernelGGL(winattn_fused, dim3(B), dim3(256), 0, stream,
        (const float*)        d_in[0],
        (const unsigned char*)d_in[1],
        (const float*)        d_in[2],
        (const float*)        d_in[3],
        (const float*)        d_in[4],
        (const float*)        d_in[5],
        (const float*)        d_in[6],
        (const int*)          d_in[7],
        (float*)              d_out);
}